// Round 9
// baseline (490.641 us; speedup 1.0000x reference)
//
#include <hip/hip_runtime.h>
#include <type_traits>

typedef __bf16 bf16x8 __attribute__((ext_vector_type(8)));
typedef __bf16 bf16x4v __attribute__((ext_vector_type(4)));
typedef float f32x4 __attribute__((ext_vector_type(4)));
typedef unsigned short u16x8 __attribute__((ext_vector_type(8)));
typedef unsigned short u16x4 __attribute__((ext_vector_type(4)));

#define NSEQ 4096
#define DM 1024
#define NBATCH 4

__device__ __forceinline__ unsigned short f2bf(float f) {
  unsigned u = __float_as_uint(f);
  u += 0x7FFFu + ((u >> 16) & 1u);
  return (unsigned short)(u >> 16);
}
__device__ __forceinline__ float bf2f(unsigned short h) {
  return __uint_as_float(((unsigned)h) << 16);
}
__device__ __forceinline__ float gelu_exact(float x) {
  return 0.5f * x * (1.0f + erff(x * 0.7071067811865475f));
}

// async global->LDS, 16B per lane; lds dst is wave-uniform base + lane*16
__device__ __forceinline__ void gload_lds16(const unsigned short* src,
                                            unsigned short* dst) {
  __builtin_amdgcn_global_load_lds(
      (const __attribute__((address_space(1))) unsigned int*)src,
      (__attribute__((address_space(3))) unsigned int*)dst, 16, 0, 0);
}

#define BAR() asm volatile("s_barrier" ::: "memory")
#define VMCNT8() asm volatile("s_waitcnt vmcnt(8)" ::: "memory")

// ---------------- LayerNorm: x (f32) -> nx (bf16) ----------------
__global__ __launch_bounds__(256) void ln_kernel(const float* __restrict__ x,
                                                 unsigned short* __restrict__ nx) {
  const int row = blockIdx.x;
  const int tid = threadIdx.x;
  const float4 v = reinterpret_cast<const float4*>(x + (size_t)row * DM)[tid];
  float s = v.x + v.y + v.z + v.w;
  float q = v.x * v.x + v.y * v.y + v.z * v.z + v.w * v.w;
#pragma unroll
  for (int off = 32; off > 0; off >>= 1) {
    s += __shfl_down(s, off);
    q += __shfl_down(q, off);
  }
  __shared__ float ss[4], sq[4];
  if ((tid & 63) == 0) {
    ss[tid >> 6] = s;
    sq[tid >> 6] = q;
  }
  __syncthreads();
  const float ts = ss[0] + ss[1] + ss[2] + ss[3];
  const float tq = sq[0] + sq[1] + sq[2] + sq[3];
  const float mu = ts * (1.0f / DM);
  const float var = tq * (1.0f / DM) - mu * mu;
  const float rs = rsqrtf(var + 1e-5f);
  u16x4 o;
  o[0] = f2bf((v.x - mu) * rs);
  o[1] = f2bf((v.y - mu) * rs);
  o[2] = f2bf((v.z - mu) * rs);
  o[3] = f2bf((v.w - mu) * rs);
  *reinterpret_cast<u16x4*>(nx + (size_t)row * DM + tid * 4) = o;
}

// ---------------- transpose+convert: in f32 [K][N] -> out bf16 [N][K] -------------
__global__ __launch_bounds__(256) void tconv_kernel(const float* __restrict__ in,
                                                    unsigned short* __restrict__ out,
                                                    int K, int N) {
  __shared__ unsigned short tile[64][72];
  const int n0 = blockIdx.x * 64;
  const int k0 = blockIdx.y * 64;
  const int tid = threadIdx.x;
  const int lr = tid >> 4, lc = (tid & 15) * 4;
#pragma unroll
  for (int p = 0; p < 4; p++) {
    const int r = lr + p * 16;
    float4 v = *reinterpret_cast<const float4*>(in + (size_t)(k0 + r) * N + n0 + lc);
    tile[r][lc + 0] = f2bf(v.x);
    tile[r][lc + 1] = f2bf(v.y);
    tile[r][lc + 2] = f2bf(v.z);
    tile[r][lc + 3] = f2bf(v.w);
  }
  __syncthreads();
  const int nn = tid >> 2, kkg = (tid & 3) * 16;
  u16x8 o0, o1;
#pragma unroll
  for (int j = 0; j < 8; j++) {
    o0[j] = tile[kkg + j][nn];
    o1[j] = tile[kkg + 8 + j][nn];
  }
  unsigned short* dst = out + (size_t)(n0 + nn) * K + k0 + kkg;
  *reinterpret_cast<u16x8*>(dst) = o0;
  *reinterpret_cast<u16x8*>(dst + 8) = o1;
}

// ---------------- 256x256 8-phase GEMM: C[M,N] = A[M,K] @ Bt[N,K] (bf16) ----------
// 512 thr = 8 waves (2M x 4N), BK=64, LDS 128 KiB as [dbuf][khalf][256][32].
// T2 swizzle: logical (row, 16B-chunk c) at physical chunk c ^ ((row>>1)&3);
// conflicts measured 0 (round 8).
// Round 9: register READ-AHEAD — phase = [stage; (vmcnt); BAR; ds_read frags for
// NEXT phase; MFMA with frags read LAST phase; BAR]. LDS-read service now
// overlaps the MFMA pipe instead of serializing with it.
// Publication check per phase (same vmcnt pacing as round 8):
//  ph0 reads A-kh0 r64-127(kt)   : published ph3(kt-1) wait+BAR
//  ph1 reads A/B-kh1(kt)         : published ph1(kt)   wait+BAR  (this phase)
//  ph2 reads A-kh1 r64-127(kt)   : published ph1(kt)
//  ph3 reads A/B-kh0(kt+1)       : published ph3(kt)   wait+BAR  (this phase)
// XCD-chunked bid swizzle (nwg % 8 == 0 for all launches).
template <bool FINAL>
__global__ __launch_bounds__(512, 2) void gemm256_kernel(
    const unsigned short* __restrict__ A, int lda,
    const unsigned short* __restrict__ Bt, int ldb, void* __restrict__ Cv,
    int ldc, int K, int ntn, const float* __restrict__ X) {
  __shared__ unsigned short Ah[2][2][8192];  // [dbuf][khalf][row*32+k]
  __shared__ unsigned short Bh[2][2][8192];
  const int tid = threadIdx.x;
  const int lane = tid & 63;
  const int w = tid >> 6;
  const int lq = lane & 15;
  const int lg = lane >> 4;
  const int wm = w >> 2;  // 0..1
  const int wn = w & 3;   // 0..3
  // XCD-chunked swizzle (bijective: gridDim.x % 8 == 0)
  const int cpx = gridDim.x >> 3;
  const int bid = (blockIdx.x & 7) * cpx + (blockIdx.x >> 3);
  const int m0 = (bid / ntn) * 256;
  const int n0 = (bid % ntn) * 256;
  const int nk = K >> 6;

  // staging geometry: chunk g = j*512 + w*64 + lane; row = g>>2, chunk = g&3.
  // source col pre-swizzled: kcS = ((g&3)*8) ^ (((row>>1)&3)<<3)
  const int g0 = w * 64 + lane;
  const int rowS = g0 >> 2;
  const int kcS = ((g0 & 3) * 8) ^ (((rowS >> 1) & 3) << 3);
  const unsigned short* Asrc = A + (size_t)(m0 + rowS) * lda + kcS;
  const unsigned short* Bsrc = Bt + (size_t)(n0 + rowS) * ldb + kcS;
  const size_t ldaj = (size_t)128 * lda;
  const size_t ldbj = (size_t)128 * ldb;
  const int dstW = w * 64 * 8;

  auto stageA = [&](int db, int kh, int kt2) {
    if (kt2 < nk) {
      const unsigned short* s = Asrc + (size_t)kt2 * 64 + kh * 32;
      unsigned short* d = &Ah[db][kh][0] + dstW;
      gload_lds16(s, d);
      gload_lds16(s + ldaj, d + 4096);
    }
  };
  auto stageB = [&](int db, int kh, int kt2) {
    if (kt2 < nk) {
      const unsigned short* s = Bsrc + (size_t)kt2 * 64 + kh * 32;
      unsigned short* d = &Bh[db][kh][0] + dstW;
      gload_lds16(s, d);
      gload_lds16(s + ldbj, d + 4096);
    }
  };

  const int aBase = wm * 128;
  const int bBase = wn * 64;
  const int cSwz = (lg * 8) ^ (((lq >> 1) & 3) << 3);

  auto loadA = [&](bf16x8* dst, int bufI, int kh, int rbase) {
#pragma unroll
    for (int i = 0; i < 4; i++)
      dst[i] = *reinterpret_cast<const bf16x8*>(
          &Ah[bufI][kh][(rbase + i * 16 + lq) * 32 + cSwz]);
  };
  auto loadB = [&](bf16x8* dst, int bufI, int kh) {
#pragma unroll
    for (int j = 0; j < 4; j++)
      dst[j] = *reinterpret_cast<const bf16x8*>(
          &Bh[bufI][kh][(bBase + j * 16 + lq) * 32 + cSwz]);
  };

  f32x4 acc[8][4];
#pragma unroll
  for (int i = 0; i < 8; i++)
#pragma unroll
    for (int j = 0; j < 4; j++)
#pragma unroll
      for (int r = 0; r < 4; r++) acc[i][j][r] = 0.0f;

  bf16x8 Ax[4], Ay[4], Ba[4], Bb[4];

  // prologue: A0,B0,A1,B1 of tile 0; A0,B0 of tile 1 (12 loads)
  stageA(0, 0, 0);
  stageB(0, 0, 0);
  stageA(0, 1, 0);
  stageB(0, 1, 0);
  stageA(1, 0, 1);
  stageB(1, 0, 1);
  VMCNT8();  // drains A0(0), B0(0)
  BAR();
  loadA(Ax, 0, 0, aBase);  // frags for ph0 of tile 0
  loadB(Ba, 0, 0);

#pragma unroll 1
  for (int kt = 0; kt < nk; ++kt) {
    const int buf = kt & 1;

    // ---- phase 0: MFMA(Ax,Ba)->acc[0..3]; prefetch Ay = A-kh0 r64-127
    stageA(buf ^ 1, 1, kt + 1);
    BAR();
    loadA(Ay, buf, 0, aBase + 64);
    __builtin_amdgcn_s_setprio(1);
#pragma unroll
    for (int i = 0; i < 4; i++)
#pragma unroll
      for (int j = 0; j < 4; j++)
        acc[i][j] =
            __builtin_amdgcn_mfma_f32_16x16x32_bf16(Ax[i], Ba[j], acc[i][j], 0, 0, 0);
    __builtin_amdgcn_s_setprio(0);
    BAR();

    // ---- phase 1: MFMA(Ay,Ba)->acc[4..7]; prefetch Ax = A-kh1 r0-63, Bb = B-kh1
    stageB(buf ^ 1, 1, kt + 1);
    VMCNT8();
    BAR();
    loadA(Ax, buf, 1, aBase);
    loadB(Bb, buf, 1);
    __builtin_amdgcn_s_setprio(1);
#pragma unroll
    for (int i = 0; i < 4; i++)
#pragma unroll
      for (int j = 0; j < 4; j++)
        acc[4 + i][j] = __builtin_amdgcn_mfma_f32_16x16x32_bf16(Ay[i], Ba[j],
                                                                acc[4 + i][j], 0, 0, 0);
    __builtin_amdgcn_s_setprio(0);
    BAR();

    // ---- phase 2: MFMA(Ax,Bb)->acc[0..3]; prefetch Ay = A-kh1 r64-127
    stageA(buf, 0, kt + 2);
    BAR();
    loadA(Ay, buf, 1, aBase + 64);
    __builtin_amdgcn_s_setprio(1);
#pragma unroll
    for (int i = 0; i < 4; i++)
#pragma unroll
      for (int j = 0; j < 4; j++)
        acc[i][j] =
            __builtin_amdgcn_mfma_f32_16x16x32_bf16(Ax[i], Bb[j], acc[i][j], 0, 0, 0);
    __builtin_amdgcn_s_setprio(0);
    BAR();

    // ---- phase 3: MFMA(Ay,Bb)->acc[4..7]; prefetch Ax,Ba of tile kt+1 (kh0)
    stageB(buf, 0, kt + 2);
    VMCNT8();
    BAR();
    loadA(Ax, buf ^ 1, 0, aBase);
    loadB(Ba, buf ^ 1, 0);
    __builtin_amdgcn_s_setprio(1);
#pragma unroll
    for (int i = 0; i < 4; i++)
#pragma unroll
      for (int j = 0; j < 4; j++)
        acc[4 + i][j] = __builtin_amdgcn_mfma_f32_16x16x32_bf16(Ay[i], Bb[j],
                                                                acc[4 + i][j], 0, 0, 0);
    __builtin_amdgcn_s_setprio(0);
    BAR();
  }

  if (FINAL) {
    float* C = reinterpret_cast<float*>(Cv);
#pragma unroll
    for (int I = 0; I < 8; I++)
#pragma unroll
      for (int j = 0; j < 4; j++)
#pragma unroll
        for (int r = 0; r < 4; r++) {
          const int row = m0 + wm * 128 + I * 16 + lg * 4 + r;
          const int col = n0 + wn * 64 + j * 16 + lq;
          const size_t off = (size_t)row * ldc + col;
          C[off] = X[off] + acc[I][j][r];
        }
  } else {
    unsigned short* C = reinterpret_cast<unsigned short*>(Cv);
#pragma unroll
    for (int I = 0; I < 8; I++)
#pragma unroll
      for (int j = 0; j < 4; j++)
#pragma unroll
        for (int r = 0; r < 4; r++) {
          const int row = m0 + wm * 128 + I * 16 + lg * 4 + r;
          const int col = n0 + wn * 64 + j * 16 + lq;
          C[(size_t)row * ldc + col] = f2bf(acc[I][j][r]);
        }
  }
}

// ---------------- gate: local = lin * gelu(pg) -> concat[:, 0:1024] ----------------
__global__ __launch_bounds__(256) void gate_local_kernel(
    const unsigned short* __restrict__ gateH, unsigned short* __restrict__ concat) {
  const int idx = blockIdx.x * 256 + threadIdx.x;
  const int row = idx >> 7;
  const int cg = idx & 127;
  const unsigned short* hr = gateH + (size_t)row * 4096;
  u16x8 lin = *reinterpret_cast<const u16x8*>(hr + cg * 8);
  u16x8 pg = *reinterpret_cast<const u16x8*>(hr + 2048 + cg * 8);
  u16x8 o;
#pragma unroll
  for (int j = 0; j < 8; j++) {
    const float l = bf2f(lin[j]);
    const float g = gelu_exact(bf2f(pg[j]));
    o[j] = f2bf(l * g);
  }
  *reinterpret_cast<u16x8*>(concat + (size_t)row * 2048 + cg * 8) = o;
}

// ---------------- gate: v = lin * gelu(pg), stored transposed vT[b][d][n] -------------
__global__ __launch_bounds__(256) void gate_vt_kernel(
    const unsigned short* __restrict__ gateH, unsigned short* __restrict__ vT) {
  __shared__ unsigned short tbuf[64][72];
  const int n0 = blockIdx.x * 64;
  const int d0 = blockIdx.y * 64;
  const int b = blockIdx.z;
  const int tid = threadIdx.x;
#pragma unroll
  for (int p = 0; p < 2; p++) {
    const int r = p * 32 + (tid >> 3);
    const int cg = tid & 7;
    const unsigned short* hr = gateH + (size_t)(b * NSEQ + n0 + r) * 4096;
    u16x8 lin = *reinterpret_cast<const u16x8*>(hr + 1024 + d0 + cg * 8);
    u16x8 pg = *reinterpret_cast<const u16x8*>(hr + 3072 + d0 + cg * 8);
    u16x8 o;
#pragma unroll
    for (int j = 0; j < 8; j++) {
      const float l = bf2f(lin[j]);
      const float g = gelu_exact(bf2f(pg[j]));
      o[j] = f2bf(l * g);
    }
    *reinterpret_cast<u16x8*>(&tbuf[r][cg * 8]) = o;
  }
  __syncthreads();
#pragma unroll
  for (int p = 0; p < 2; p++) {
    const int d = p * 32 + (tid >> 3);
    const int ng = tid & 7;
    u16x8 o;
#pragma unroll
    for (int j = 0; j < 8; j++) o[j] = tbuf[ng * 8 + j][d];
    *reinterpret_cast<u16x8*>(vT + (size_t)(b * DM + d0 + d) * NSEQ + n0 +
                              ng * 8) = o;
  }
}

// ---------------- P kernel: one causal 128x128 tile per block --------------------
#define P_TILE 16384           // 128*128
#define P_PER_B 8650752        // 528 tiles * 16384
__global__ __launch_bounds__(512, 4) void pk_kernel(
    const unsigned short* __restrict__ qk, const float* __restrict__ pbm_ptr,
    unsigned short* __restrict__ P, float* __restrict__ l) {
  __shared__ unsigned short Ks[128][136];
  const int tid = threadIdx.x;
  const int lane = tid & 63;
  const int w = tid >> 6;
  const int lq = lane & 15;
  const int lg = lane >> 4;
  const int bid = blockIdx.x;
  const int b = bid / 528;
  const int t = bid - b * 528;
  int qt = (int)((sqrtf((float)(8 * t + 1)) - 1.0f) * 0.5f);
  while ((qt + 1) * (qt + 2) / 2 <= t) ++qt;
  while (qt * (qt + 1) / 2 > t) --qt;
  const int kt = t - qt * (qt + 1) / 2;
  const float pbm = *pbm_ptr;
  const float SCALE = 0.08838834764831845f;

  const unsigned short* qb = qk + (size_t)b * NSEQ * 256;

#pragma unroll
  for (int p = 0; p < 4; p++) {
    const int task = tid + p * 512;
    const int row = task >> 4;
    const int ch = task & 15;
    bf16x8 v = *reinterpret_cast<const bf16x8*>(
        qb + (size_t)(kt * 128 + row) * 256 + 128 + ch * 8);
    *reinterpret_cast<bf16x8*>(&Ks[row][ch * 8]) = v;
  }
  const int qloc = w * 16 + lq;
  bf16x8 qf[4];
#pragma unroll
  for (int ks = 0; ks < 4; ks++)
    qf[ks] = *reinterpret_cast<const bf16x8*>(
        qb + (size_t)(qt * 128 + qloc) * 256 + ks * 32 + lg * 8);
  __syncthreads();

  f32x4 sa[8];
#pragma unroll
  for (int sub = 0; sub < 8; sub++)
#pragma unroll
    for (int r = 0; r < 4; r++) sa[sub][r] = 0.0f;
#pragma unroll
  for (int ks = 0; ks < 4; ks++)
#pragma unroll
    for (int sub = 0; sub < 8; sub++) {
      bf16x8 kf =
          *reinterpret_cast<const bf16x8*>(&Ks[sub * 16 + lq][ks * 32 + lg * 8]);
      sa[sub] = __builtin_amdgcn_mfma_f32_16x16x32_bf16(kf, qf[ks], sa[sub], 0, 0, 0);
    }
  const size_t KL = (size_t)(qt + 1) * 128;
  unsigned short* Prow = P + (size_t)b * P_PER_B +
                         (size_t)(qt * (qt + 1) / 2) * P_TILE + (size_t)qloc * KL +
                         kt * 128;
  float ps = 0.0f;
  const bool diag = (kt == qt);
#pragma unroll
  for (int sub = 0; sub < 8; sub++) {
    bf16x4v pv;
#pragma unroll
    for (int r = 0; r < 4; r++) {
      const int kvloc = sub * 16 + lg * 4 + r;
      float p;
      if (diag && kvloc > qloc) {
        p = 0.0f;
      } else {
        const float dn = (float)((kt - qt) * 128 + kvloc - qloc) + pbm;
        const float s = sa[sub][r] * SCALE + 1.0f / (1.0f + __expf(-dn));
        p = __expf(s);
      }
      ps += p;
      pv[r] = (__bf16)p;
    }
    *reinterpret_cast<bf16x4v*>(Prow + sub * 16 + lg * 4) = pv;
  }
  ps += __shfl_xor(ps, 16);
  ps += __shfl_xor(ps, 32);
  if (lane < 16) atomicAdd(&l[b * NSEQ + qt * 128 + w * 16 + lane], ps);
}

// ---------------- PV kernel: O[128, 128] = P[128, KL] @ vT^T, /l, -> concat ------
// T2 swizzle on [128][64]-ushort tiles: chunk col ^= (row&7)  (16B chunks).
__global__ __launch_bounds__(256, 4) void pv_kernel(
    const unsigned short* __restrict__ P, const unsigned short* __restrict__ vT,
    const float* __restrict__ l, unsigned short* __restrict__ concat) {
  __shared__ unsigned short As[128][64];
  __shared__ unsigned short Bs[128][64];
  const int tid = threadIdx.x;
  const int bid = blockIdx.x;
  const int qt = 31 - (bid >> 5);  // heavy tiles dispatched first
  const int rest = bid & 31;
  const int b = rest >> 3;
  const int nt = rest & 7;
  const int KL = (qt + 1) * 128;
  const unsigned short* A =
      P + (size_t)b * P_PER_B + (size_t)(qt * (qt + 1) / 2) * P_TILE;
  const unsigned short* Bt = vT + (size_t)b * DM * NSEQ;
  const int n0 = nt * 128;
  const int lane = tid & 63;
  const int w = tid >> 6;
  const int lr = lane & 15;
  const int lg = lane >> 4;
  const int wr = (w >> 1) * 64;
  const int wc = (w & 1) * 64;
  const int rSwz = (lr & 7) << 3;  // read-side swizzle (row&7 == lr&7)

  f32x4 acc[4][4];
#pragma unroll
  for (int i = 0; i < 4; i++)
#pragma unroll
    for (int j = 0; j < 4; j++)
#pragma unroll
      for (int r = 0; r < 4; r++) acc[i][j][r] = 0.0f;

  for (int k0 = 0; k0 < KL; k0 += 64) {
#pragma unroll
    for (int j = 0; j < 4; j++) {
      const int boff = w * 4096 + j * 1024 + lane * 16;
      const int row = boff >> 7;
      const int col = (((boff & 127) >> 1)) ^ ((row & 7) << 3);  // src pre-swizzle
      gload_lds16(A + (size_t)row * KL + k0 + col,
                  &As[0][0] + (boff - lane * 16) / 2);
    }
#pragma unroll
    for (int j = 0; j < 4; j++) {
      const int boff = w * 4096 + j * 1024 + lane * 16;
      const int row = boff >> 7;
      const int col = (((boff & 127) >> 1)) ^ ((row & 7) << 3);
      gload_lds16(Bt + (size_t)(n0 + row) * NSEQ + k0 + col,
                  &Bs[0][0] + (boff - lane * 16) / 2);
    }
    __syncthreads();
#pragma unroll
    for (int kk = 0; kk < 64; kk += 32) {
      bf16x8 af[4], bfr[4];
#pragma unroll
      for (int i = 0; i < 4; i++)
        af[i] = *reinterpret_cast<const bf16x8*>(
            &As[wr + i * 16 + lr][(kk + lg * 8) ^ rSwz]);
#pragma unroll
      for (int j = 0; j < 4; j++)
        bfr[j] = *reinterpret_cast<const bf16x8*>(
            &Bs[wc + j * 16 + lr][(kk + lg * 8) ^ rSwz]);
#pragma unroll
      for (int i = 0; i < 4; i++)
#pragma unroll
        for (int j = 0; j < 4; j++)
          acc[i][j] = __builtin_amdgcn_mfma_f32_16x16x32_bf16(af[i], bfr[j],
                                                              acc[i][j], 0, 0, 0);
    }
    __syncthreads();
  }

  const float* lb = l + b * NSEQ + qt * 128;
#pragma unroll
  for (int i = 0; i < 4; i++) {
    f32x4 lv = *reinterpret_cast<const f32x4*>(&lb[wr + i * 16 + lg * 4]);
    f32x4 inv;
#pragma unroll
    for (int r = 0; r < 4; r++) inv[r] = 1.0f / lv[r];
#pragma unroll
    for (int j = 0; j < 4; j++)
#pragma unroll
      for (int r = 0; r < 4; r++) {
        const int grow = b * NSEQ + qt * 128 + wr + i * 16 + lg * 4 + r;
        const int col = 1024 + n0 + wc + j * 16 + lr;
        concat[(size_t)grow * 2048 + col] = f2bf(acc[i][j][r] * inv[r]);
      }
  }
}

extern "C" void kernel_launch(void* const* d_in, const int* in_sizes, int n_in,
                              void* d_out, int out_size, void* d_ws,
                              size_t ws_size, hipStream_t stream) {
  (void)in_sizes;
  (void)n_in;
  (void)out_size;
  const float* x = (const float*)d_in[0];
  const float* expand = (const float*)d_in[1];
  const float* project = (const float*)d_in[2];
  const float* pbm = (const float*)d_in[3];
  float* out = (float*)d_out;

  const size_t QK_BYTES = (size_t)16384 * 256 * 2;
  const size_t GH_BYTES = (size_t)16384 * 4096 * 2;
  const size_t CAT_BYTES = (size_t)16384 * 2048 * 2;
  const size_t NX_BYTES = (size_t)16384 * DM * 2;
  const size_t P_BYTES = (size_t)NBATCH * P_PER_B * 2;  // 69.2 MB
  if (ws_size < QK_BYTES + GH_BYTES + CAT_BYTES + NX_BYTES) return;

  char* ws = (char*)d_ws;
  unsigned short* qk = (unsigned short*)ws;
  unsigned short* gateH = (unsigned short*)(ws + QK_BYTES);
  unsigned short* concat = (unsigned short*)(ws + QK_BYTES + GH_BYTES);
  unsigned short* nx = (unsigned short*)(ws + QK_BYTES + GH_BYTES + CAT_BYTES);
  unsigned short* vT = nx;
  unsigned short* projectT = nx;
  unsigned short* expandT = concat;
  unsigned short* P = gateH;
  float* l = (float*)(ws + QK_BYTES + P_BYTES);

  // 0a. expandT[n][k] = bf16(expand[k][n])
  tconv_kernel<<<dim3(68, 16), 256, 0, stream>>>(expand, expandT, 1024, 4352);
  // 1. LayerNorm
  ln_kernel<<<16384, 256, 0, stream>>>(x, nx);
  // 2a. qk = nx @ expandT[0:256]^T   (M=16384, N=256, K=1024)
  gemm256_kernel<false><<<dim3(64), 512, 0, stream>>>(
      nx, DM, expandT, DM, (void*)qk, 256, DM, 1, nullptr);
  // 2b. gateH = nx @ expandT[256:4352]^T  (M=16384, N=4096, K=1024)
  gemm256_kernel<false><<<dim3(64 * 16), 512, 0, stream>>>(
      nx, DM, expandT + (size_t)256 * DM, DM, (void*)gateH, 4096, DM, 16, nullptr);
  // 3. local half of concat
  gate_local_kernel<<<8192, 256, 0, stream>>>(gateH, concat);
  // 4. v transposed (nx dead)
  gate_vt_kernel<<<dim3(64, 16, 4), 256, 0, stream>>>(gateH, vT);
  // 5. P = softmax numerator (gateH dead -> P aliases it); l zeroed first
  hipMemsetAsync(l, 0, (size_t)NBATCH * NSEQ * 4, stream);
  pk_kernel<<<dim3(NBATCH * 528), 512, 0, stream>>>(qk, pbm, P, l);
  // 6. attn = (P @ V) / l -> concat[:, 1024:2048]
  pv_kernel<<<dim3(1024), 256, 0, stream>>>(P, vT, l, concat);
  // 7. projectT (vT dead)
  tconv_kernel<<<dim3(16, 32), 256, 0, stream>>>(project, projectT, 2048, DM);
  // 8. out = x + concat @ projectT^T  (M=16384, N=1024, K=2048)
  gemm256_kernel<true><<<dim3(64 * 4), 512, 0, stream>>>(
      concat, 2048, projectT, 2048, (void*)out, DM, 2048, 4, x);
}

// Round 10
// 471.611 us; speedup vs baseline: 1.0404x; 1.0404x over previous
//
#include <hip/hip_runtime.h>
#include <type_traits>

typedef __bf16 bf16x8 __attribute__((ext_vector_type(8)));
typedef __bf16 bf16x4v __attribute__((ext_vector_type(4)));
typedef float f32x4 __attribute__((ext_vector_type(4)));
typedef unsigned short u16x8 __attribute__((ext_vector_type(8)));
typedef unsigned short u16x4 __attribute__((ext_vector_type(4)));

#define NSEQ 4096
#define DM 1024
#define NBATCH 4

__device__ __forceinline__ unsigned short f2bf(float f) {
  unsigned u = __float_as_uint(f);
  u += 0x7FFFu + ((u >> 16) & 1u);
  return (unsigned short)(u >> 16);
}
__device__ __forceinline__ float bf2f(unsigned short h) {
  return __uint_as_float(((unsigned)h) << 16);
}
__device__ __forceinline__ float gelu_exact(float x) {
  return 0.5f * x * (1.0f + erff(x * 0.7071067811865475f));
}

// async global->LDS, 16B per lane; lds dst is wave-uniform base + lane*16
__device__ __forceinline__ void gload_lds16(const unsigned short* src,
                                            unsigned short* dst) {
  __builtin_amdgcn_global_load_lds(
      (const __attribute__((address_space(1))) unsigned int*)src,
      (__attribute__((address_space(3))) unsigned int*)dst, 16, 0, 0);
}

#define BAR() asm volatile("s_barrier" ::: "memory")
#define VMCNT8() asm volatile("s_waitcnt vmcnt(8)" ::: "memory")

// column permutation for expandT': pairs lin (cols 256..2303) and pg
// (cols 2304..4351) into 64-col physical blocks [lin 32 | pg 32] so the
// gate GEMM epilogue holds both operands of gated[c] in one thread.
__device__ __forceinline__ int perm_col(int n) {
  if (n < 256) return n;
  int c = n - 256;
  if (c < 2048) return 256 + ((c >> 5) << 6) + (c & 31);
  c -= 2048;
  return 256 + ((c >> 5) << 6) + 32 + (c & 31);
}

// ---------------- LayerNorm: x (f32) -> nx (bf16) ----------------
__global__ __launch_bounds__(256) void ln_kernel(const float* __restrict__ x,
                                                 unsigned short* __restrict__ nx) {
  const int row = blockIdx.x;
  const int tid = threadIdx.x;
  const float4 v = reinterpret_cast<const float4*>(x + (size_t)row * DM)[tid];
  float s = v.x + v.y + v.z + v.w;
  float q = v.x * v.x + v.y * v.y + v.z * v.z + v.w * v.w;
#pragma unroll
  for (int off = 32; off > 0; off >>= 1) {
    s += __shfl_down(s, off);
    q += __shfl_down(q, off);
  }
  __shared__ float ss[4], sq[4];
  if ((tid & 63) == 0) {
    ss[tid >> 6] = s;
    sq[tid >> 6] = q;
  }
  __syncthreads();
  const float ts = ss[0] + ss[1] + ss[2] + ss[3];
  const float tq = sq[0] + sq[1] + sq[2] + sq[3];
  const float mu = ts * (1.0f / DM);
  const float var = tq * (1.0f / DM) - mu * mu;
  const float rs = rsqrtf(var + 1e-5f);
  u16x4 o;
  o[0] = f2bf((v.x - mu) * rs);
  o[1] = f2bf((v.y - mu) * rs);
  o[2] = f2bf((v.z - mu) * rs);
  o[3] = f2bf((v.w - mu) * rs);
  *reinterpret_cast<u16x4*>(nx + (size_t)row * DM + tid * 4) = o;
}

// ------- transpose+convert: in f32 [K][N] -> out bf16 [N][K], optional perm ------
template <bool PERM>
__global__ __launch_bounds__(256) void tconv_kernel(const float* __restrict__ in,
                                                    unsigned short* __restrict__ out,
                                                    int K, int N) {
  __shared__ unsigned short tile[64][72];
  const int n0 = blockIdx.x * 64;
  const int k0 = blockIdx.y * 64;
  const int tid = threadIdx.x;
  const int lr = tid >> 4, lc = (tid & 15) * 4;
#pragma unroll
  for (int p = 0; p < 4; p++) {
    const int r = lr + p * 16;
    float4 v = *reinterpret_cast<const float4*>(in + (size_t)(k0 + r) * N + n0 + lc);
    tile[r][lc + 0] = f2bf(v.x);
    tile[r][lc + 1] = f2bf(v.y);
    tile[r][lc + 2] = f2bf(v.z);
    tile[r][lc + 3] = f2bf(v.w);
  }
  __syncthreads();
  const int nn = tid >> 2, kkg = (tid & 3) * 16;
  u16x8 o0, o1;
#pragma unroll
  for (int j = 0; j < 8; j++) {
    o0[j] = tile[kkg + j][nn];
    o1[j] = tile[kkg + 8 + j][nn];
  }
  const int orow = PERM ? perm_col(n0 + nn) : (n0 + nn);
  unsigned short* dst = out + (size_t)orow * K + k0 + kkg;
  *reinterpret_cast<u16x8*>(dst) = o0;
  *reinterpret_cast<u16x8*>(dst + 8) = o1;
}

// ---------------- 256x256 8-phase GEMM: C[M,N] = A[M,K] @ Bt[N,K] (bf16) ----------
// Round-8 schedule (proven best): phase = [ds_reads; stage; (vmcnt); BAR; MFMA; BAR].
// MODE 0: bf16 store. MODE 1: f32 out = X + A@Bt^T. MODE 2: gated epilogue —
// Bt is the permuted gate region ([lin32|pg32] blocks); per thread acc[I][0..1]
// = lin, acc[I][2..3] = pg of the SAME gated cols; writes lin*gelu(pg) to
// concat (c<1024) or vbuf (c>=1024). ldc/X unused in MODE 2.
template <int MODE>
__global__ __launch_bounds__(512, 2) void gemm256_kernel(
    const unsigned short* __restrict__ A, int lda,
    const unsigned short* __restrict__ Bt, int ldb, void* __restrict__ Cv,
    void* __restrict__ Cv2, int ldc, int K, int ntn,
    const float* __restrict__ X) {
  __shared__ unsigned short Ah[2][2][8192];  // [dbuf][khalf][row*32+k]
  __shared__ unsigned short Bh[2][2][8192];
  const int tid = threadIdx.x;
  const int lane = tid & 63;
  const int w = tid >> 6;
  const int lq = lane & 15;
  const int lg = lane >> 4;
  const int wm = w >> 2;  // 0..1
  const int wn = w & 3;   // 0..3
  const int bid = blockIdx.x;
  const int m0 = (bid / ntn) * 256;
  const int n0 = (bid % ntn) * 256;
  const int nk = K >> 6;

  const int g0 = w * 64 + lane;
  const int rowS = g0 >> 2;
  const int kcS = ((g0 & 3) * 8) ^ (((rowS >> 1) & 3) << 3);
  const unsigned short* Asrc = A + (size_t)(m0 + rowS) * lda + kcS;
  const unsigned short* Bsrc = Bt + (size_t)(n0 + rowS) * ldb + kcS;
  const size_t ldaj = (size_t)128 * lda;
  const size_t ldbj = (size_t)128 * ldb;
  const int dstW = w * 64 * 8;

  auto stageA = [&](int db, int kh, int kt2) {
    if (kt2 < nk) {
      const unsigned short* s = Asrc + (size_t)kt2 * 64 + kh * 32;
      unsigned short* d = &Ah[db][kh][0] + dstW;
      gload_lds16(s, d);
      gload_lds16(s + ldaj, d + 4096);
    }
  };
  auto stageB = [&](int db, int kh, int kt2) {
    if (kt2 < nk) {
      const unsigned short* s = Bsrc + (size_t)kt2 * 64 + kh * 32;
      unsigned short* d = &Bh[db][kh][0] + dstW;
      gload_lds16(s, d);
      gload_lds16(s + ldbj, d + 4096);
    }
  };

  f32x4 acc[8][4];
#pragma unroll
  for (int i = 0; i < 8; i++)
#pragma unroll
    for (int j = 0; j < 4; j++)
#pragma unroll
      for (int r = 0; r < 4; r++) acc[i][j][r] = 0.0f;

  stageA(0, 0, 0);
  stageB(0, 0, 0);
  stageA(0, 1, 0);
  stageB(0, 1, 0);
  stageA(1, 0, 1);
  stageB(1, 0, 1);
  VMCNT8();
  BAR();

  const int aBase = wm * 128;
  const int bBase = wn * 64;
  const int cSwz = (lg * 8) ^ (((lq >> 1) & 3) << 3);

#pragma unroll 1
  for (int kt = 0; kt < nk; ++kt) {
    const int buf = kt & 1;
    bf16x8 af[4], bf0[4], bf1[4];

    // ---- phase 0: kh0, rows 0-63; stage A-kh1(kt+1)
#pragma unroll
    for (int i = 0; i < 4; i++)
      af[i] = *reinterpret_cast<const bf16x8*>(
          &Ah[buf][0][(aBase + i * 16 + lq) * 32 + cSwz]);
#pragma unroll
    for (int j = 0; j < 4; j++)
      bf0[j] = *reinterpret_cast<const bf16x8*>(
          &Bh[buf][0][(bBase + j * 16 + lq) * 32 + cSwz]);
    stageA(buf ^ 1, 1, kt + 1);
    BAR();
    __builtin_amdgcn_s_setprio(1);
#pragma unroll
    for (int i = 0; i < 4; i++)
#pragma unroll
      for (int j = 0; j < 4; j++)
        acc[i][j] =
            __builtin_amdgcn_mfma_f32_16x16x32_bf16(af[i], bf0[j], acc[i][j], 0, 0, 0);
    __builtin_amdgcn_s_setprio(0);
    BAR();

    // ---- phase 1: kh0, rows 64-127; stage B-kh1(kt+1); vmcnt(8)
#pragma unroll
    for (int i = 0; i < 4; i++)
      af[i] = *reinterpret_cast<const bf16x8*>(
          &Ah[buf][0][(aBase + 64 + i * 16 + lq) * 32 + cSwz]);
    stageB(buf ^ 1, 1, kt + 1);
    VMCNT8();
    BAR();
    __builtin_amdgcn_s_setprio(1);
#pragma unroll
    for (int i = 0; i < 4; i++)
#pragma unroll
      for (int j = 0; j < 4; j++)
        acc[4 + i][j] = __builtin_amdgcn_mfma_f32_16x16x32_bf16(af[i], bf0[j],
                                                                acc[4 + i][j], 0, 0, 0);
    __builtin_amdgcn_s_setprio(0);
    BAR();

    // ---- phase 2: kh1, rows 0-63; stage A-kh0(kt+2)
#pragma unroll
    for (int i = 0; i < 4; i++)
      af[i] = *reinterpret_cast<const bf16x8*>(
          &Ah[buf][1][(aBase + i * 16 + lq) * 32 + cSwz]);
#pragma unroll
    for (int j = 0; j < 4; j++)
      bf1[j] = *reinterpret_cast<const bf16x8*>(
          &Bh[buf][1][(bBase + j * 16 + lq) * 32 + cSwz]);
    stageA(buf, 0, kt + 2);
    BAR();
    __builtin_amdgcn_s_setprio(1);
#pragma unroll
    for (int i = 0; i < 4; i++)
#pragma unroll
      for (int j = 0; j < 4; j++)
        acc[i][j] =
            __builtin_amdgcn_mfma_f32_16x16x32_bf16(af[i], bf1[j], acc[i][j], 0, 0, 0);
    __builtin_amdgcn_s_setprio(0);
    BAR();

    // ---- phase 3: kh1, rows 64-127; stage B-kh0(kt+2); vmcnt(8)
#pragma unroll
    for (int i = 0; i < 4; i++)
      af[i] = *reinterpret_cast<const bf16x8*>(
          &Ah[buf][1][(aBase + 64 + i * 16 + lq) * 32 + cSwz]);
    stageB(buf, 0, kt + 2);
    VMCNT8();
    BAR();
    __builtin_amdgcn_s_setprio(1);
#pragma unroll
    for (int i = 0; i < 4; i++)
#pragma unroll
      for (int j = 0; j < 4; j++)
        acc[4 + i][j] = __builtin_amdgcn_mfma_f32_16x16x32_bf16(af[i], bf1[j],
                                                                acc[4 + i][j], 0, 0, 0);
    __builtin_amdgcn_s_setprio(0);
    BAR();
  }

  if (MODE == 1) {
    float* C = reinterpret_cast<float*>(Cv);
#pragma unroll
    for (int I = 0; I < 8; I++)
#pragma unroll
      for (int j = 0; j < 4; j++)
#pragma unroll
        for (int r = 0; r < 4; r++) {
          const int row = m0 + wm * 128 + I * 16 + lg * 4 + r;
          const int col = n0 + wn * 64 + j * 16 + lq;
          const size_t off = (size_t)row * ldc + col;
          C[off] = X[off] + acc[I][j][r];
        }
  } else if (MODE == 0) {
    unsigned short* C = reinterpret_cast<unsigned short*>(Cv);
#pragma unroll
    for (int I = 0; I < 8; I++)
#pragma unroll
      for (int j = 0; j < 4; j++)
#pragma unroll
        for (int r = 0; r < 4; r++) {
          const int row = m0 + wm * 128 + I * 16 + lg * 4 + r;
          const int col = n0 + wn * 64 + j * 16 + lq;
          C[(size_t)row * ldc + col] = f2bf(acc[I][j][r]);
        }
  } else {
    // MODE 2: gated. physical slice (n0+wn*64) -> gated col base pi*32.
    unsigned short* concat = reinterpret_cast<unsigned short*>(Cv);
    unsigned short* vbuf = reinterpret_cast<unsigned short*>(Cv2);
    const int pi = (n0 + wn * 64) >> 6;
    const int cBase = pi * 32;
#pragma unroll
    for (int I = 0; I < 8; I++)
#pragma unroll
      for (int j = 0; j < 2; j++) {
        const int c = cBase + j * 16 + lq;
#pragma unroll
        for (int r = 0; r < 4; r++) {
          const int row = m0 + wm * 128 + I * 16 + lg * 4 + r;
          const float g = acc[I][j][r] * gelu_exact(acc[I][j + 2][r]);
          if (c < 1024)
            concat[(size_t)row * 2048 + c] = f2bf(g);
          else
            vbuf[(size_t)row * 1024 + (c - 1024)] = f2bf(g);
        }
      }
  }
}

// ---------------- v transpose: vbuf[n][1024] -> vT[b][d][n] ----------------
__global__ __launch_bounds__(256) void vt_kernel(
    const unsigned short* __restrict__ vbuf, unsigned short* __restrict__ vT) {
  __shared__ unsigned short tbuf[64][72];
  const int n0 = blockIdx.x * 64;
  const int d0 = blockIdx.y * 64;
  const int b = blockIdx.z;
  const int tid = threadIdx.x;
#pragma unroll
  for (int p = 0; p < 2; p++) {
    const int r = p * 32 + (tid >> 3);
    const int cg = tid & 7;
    u16x8 v = *reinterpret_cast<const u16x8*>(
        vbuf + (size_t)(b * NSEQ + n0 + r) * 1024 + d0 + cg * 8);
    *reinterpret_cast<u16x8*>(&tbuf[r][cg * 8]) = v;
  }
  __syncthreads();
#pragma unroll
  for (int p = 0; p < 2; p++) {
    const int d = p * 32 + (tid >> 3);
    const int ng = tid & 7;
    u16x8 o;
#pragma unroll
    for (int j = 0; j < 8; j++) o[j] = tbuf[ng * 8 + j][d];
    *reinterpret_cast<u16x8*>(vT + (size_t)(b * DM + d0 + d) * NSEQ + n0 +
                              ng * 8) = o;
  }
}

// ---------------- P kernel: one causal 128x128 tile per block --------------------
#define P_TILE 16384           // 128*128
#define P_PER_B 8650752        // 528 tiles * 16384
__global__ __launch_bounds__(512, 4) void pk_kernel(
    const unsigned short* __restrict__ qk, const float* __restrict__ pbm_ptr,
    unsigned short* __restrict__ P, float* __restrict__ l) {
  __shared__ unsigned short Ks[128][136];
  const int tid = threadIdx.x;
  const int lane = tid & 63;
  const int w = tid >> 6;
  const int lq = lane & 15;
  const int lg = lane >> 4;
  const int bid = blockIdx.x;
  const int b = bid / 528;
  const int t = bid - b * 528;
  int qt = (int)((sqrtf((float)(8 * t + 1)) - 1.0f) * 0.5f);
  while ((qt + 1) * (qt + 2) / 2 <= t) ++qt;
  while (qt * (qt + 1) / 2 > t) --qt;
  const int kt = t - qt * (qt + 1) / 2;
  const float pbm = *pbm_ptr;
  const float SCALE = 0.08838834764831845f;

  const unsigned short* qb = qk + (size_t)b * NSEQ * 256;

#pragma unroll
  for (int p = 0; p < 4; p++) {
    const int task = tid + p * 512;
    const int row = task >> 4;
    const int ch = task & 15;
    bf16x8 v = *reinterpret_cast<const bf16x8*>(
        qb + (size_t)(kt * 128 + row) * 256 + 128 + ch * 8);
    *reinterpret_cast<bf16x8*>(&Ks[row][ch * 8]) = v;
  }
  const int qloc = w * 16 + lq;
  bf16x8 qf[4];
#pragma unroll
  for (int ks = 0; ks < 4; ks++)
    qf[ks] = *reinterpret_cast<const bf16x8*>(
        qb + (size_t)(qt * 128 + qloc) * 256 + ks * 32 + lg * 8);
  __syncthreads();

  f32x4 sa[8];
#pragma unroll
  for (int sub = 0; sub < 8; sub++)
#pragma unroll
    for (int r = 0; r < 4; r++) sa[sub][r] = 0.0f;
#pragma unroll
  for (int ks = 0; ks < 4; ks++)
#pragma unroll
    for (int sub = 0; sub < 8; sub++) {
      bf16x8 kf =
          *reinterpret_cast<const bf16x8*>(&Ks[sub * 16 + lq][ks * 32 + lg * 8]);
      sa[sub] = __builtin_amdgcn_mfma_f32_16x16x32_bf16(kf, qf[ks], sa[sub], 0, 0, 0);
    }
  const size_t KL = (size_t)(qt + 1) * 128;
  unsigned short* Prow = P + (size_t)b * P_PER_B +
                         (size_t)(qt * (qt + 1) / 2) * P_TILE + (size_t)qloc * KL +
                         kt * 128;
  float ps = 0.0f;
  const bool diag = (kt == qt);
#pragma unroll
  for (int sub = 0; sub < 8; sub++) {
    bf16x4v pv;
#pragma unroll
    for (int r = 0; r < 4; r++) {
      const int kvloc = sub * 16 + lg * 4 + r;
      float p;
      if (diag && kvloc > qloc) {
        p = 0.0f;
      } else {
        const float dn = (float)((kt - qt) * 128 + kvloc - qloc) + pbm;
        const float s = sa[sub][r] * SCALE + 1.0f / (1.0f + __expf(-dn));
        p = __expf(s);
      }
      ps += p;
      pv[r] = (__bf16)p;
    }
    *reinterpret_cast<bf16x4v*>(Prow + sub * 16 + lg * 4) = pv;
  }
  ps += __shfl_xor(ps, 16);
  ps += __shfl_xor(ps, 32);
  if (lane < 16) atomicAdd(&l[b * NSEQ + qt * 128 + w * 16 + lane], ps);
}

// ---------------- PV kernel: O[128, 128] = P[128, KL] @ vT^T, /l, -> concat ------
__global__ __launch_bounds__(256, 4) void pv_kernel(
    const unsigned short* __restrict__ P, const unsigned short* __restrict__ vT,
    const float* __restrict__ l, unsigned short* __restrict__ concat) {
  __shared__ unsigned short As[128][64];
  __shared__ unsigned short Bs[128][64];
  const int tid = threadIdx.x;
  const int bid = blockIdx.x;
  const int qt = 31 - (bid >> 5);
  const int rest = bid & 31;
  const int b = rest >> 3;
  const int nt = rest & 7;
  const int KL = (qt + 1) * 128;
  const unsigned short* A =
      P + (size_t)b * P_PER_B + (size_t)(qt * (qt + 1) / 2) * P_TILE;
  const unsigned short* Bt = vT + (size_t)b * DM * NSEQ;
  const int n0 = nt * 128;
  const int lane = tid & 63;
  const int w = tid >> 6;
  const int lr = lane & 15;
  const int lg = lane >> 4;
  const int wr = (w >> 1) * 64;
  const int wc = (w & 1) * 64;
  const int rSwz = (lr & 7) << 3;

  f32x4 acc[4][4];
#pragma unroll
  for (int i = 0; i < 4; i++)
#pragma unroll
    for (int j = 0; j < 4; j++)
#pragma unroll
      for (int r = 0; r < 4; r++) acc[i][j][r] = 0.0f;

  for (int k0 = 0; k0 < KL; k0 += 64) {
#pragma unroll
    for (int j = 0; j < 4; j++) {
      const int boff = w * 4096 + j * 1024 + lane * 16;
      const int row = boff >> 7;
      const int col = (((boff & 127) >> 1)) ^ ((row & 7) << 3);
      gload_lds16(A + (size_t)row * KL + k0 + col,
                  &As[0][0] + (boff - lane * 16) / 2);
    }
#pragma unroll
    for (int j = 0; j < 4; j++) {
      const int boff = w * 4096 + j * 1024 + lane * 16;
      const int row = boff >> 7;
      const int col = (((boff & 127) >> 1)) ^ ((row & 7) << 3);
      gload_lds16(Bt + (size_t)(n0 + row) * NSEQ + k0 + col,
                  &Bs[0][0] + (boff - lane * 16) / 2);
    }
    __syncthreads();
#pragma unroll
    for (int kk = 0; kk < 64; kk += 32) {
      bf16x8 af[4], bfr[4];
#pragma unroll
      for (int i = 0; i < 4; i++)
        af[i] = *reinterpret_cast<const bf16x8*>(
            &As[wr + i * 16 + lr][(kk + lg * 8) ^ rSwz]);
#pragma unroll
      for (int j = 0; j < 4; j++)
        bfr[j] = *reinterpret_cast<const bf16x8*>(
            &Bs[wc + j * 16 + lr][(kk + lg * 8) ^ rSwz]);
#pragma unroll
      for (int i = 0; i < 4; i++)
#pragma unroll
        for (int j = 0; j < 4; j++)
          acc[i][j] = __builtin_amdgcn_mfma_f32_16x16x32_bf16(af[i], bfr[j],
                                                              acc[i][j], 0, 0, 0);
    }
    __syncthreads();
  }

  const float* lb = l + b * NSEQ + qt * 128;
#pragma unroll
  for (int i = 0; i < 4; i++) {
    f32x4 lv = *reinterpret_cast<const f32x4*>(&lb[wr + i * 16 + lg * 4]);
    f32x4 inv;
#pragma unroll
    for (int r = 0; r < 4; r++) inv[r] = 1.0f / lv[r];
#pragma unroll
    for (int j = 0; j < 4; j++)
#pragma unroll
      for (int r = 0; r < 4; r++) {
        const int grow = b * NSEQ + qt * 128 + wr + i * 16 + lg * 4 + r;
        const int col = 1024 + n0 + wc + j * 16 + lr;
        concat[(size_t)grow * 2048 + col] = f2bf(acc[i][j][r] * inv[r]);
      }
  }
}

extern "C" void kernel_launch(void* const* d_in, const int* in_sizes, int n_in,
                              void* d_out, int out_size, void* d_ws,
                              size_t ws_size, hipStream_t stream) {
  (void)in_sizes;
  (void)n_in;
  (void)out_size;
  const float* x = (const float*)d_in[0];
  const float* expand = (const float*)d_in[1];
  const float* project = (const float*)d_in[2];
  const float* pbm = (const float*)d_in[3];
  float* out = (float*)d_out;

  // Region map (max offset 142.6+67.1+33.6 = 243.3 MB):
  // [0, 8.4)      qk [16384][256]
  // [8.4, 41.9)   vbuf [16384][1024]
  // [41.9, 111.2) P (causal-packed)
  // [111.2, +64K) l
  // [111.3, 120.2) expandT' (permuted, 4352x1024)
  // [142.6, 209.7) concat
  // [209.7, 243.3) nx -> vT -> projectT (sequential lifetimes)
  const size_t QK_BYTES = (size_t)16384 * 256 * 2;
  const size_t VBUF_BYTES = (size_t)16384 * 1024 * 2;
  const size_t P_BYTES = (size_t)NBATCH * P_PER_B * 2;
  const size_t L_BYTES = (size_t)NBATCH * NSEQ * 4;
  const size_t GH_BYTES = (size_t)16384 * 4096 * 2;
  const size_t CAT_BYTES = (size_t)16384 * 2048 * 2;
  const size_t NX_BYTES = (size_t)16384 * DM * 2;
  if (ws_size < QK_BYTES + GH_BYTES + CAT_BYTES + NX_BYTES) return;

  char* ws = (char*)d_ws;
  unsigned short* qk = (unsigned short*)ws;
  unsigned short* vbuf = (unsigned short*)(ws + QK_BYTES);
  unsigned short* P = (unsigned short*)(ws + QK_BYTES + VBUF_BYTES);
  float* l = (float*)(ws + QK_BYTES + VBUF_BYTES + P_BYTES);
  unsigned short* expandT =
      (unsigned short*)(ws + QK_BYTES + VBUF_BYTES + P_BYTES + L_BYTES);
  unsigned short* concat = (unsigned short*)(ws + QK_BYTES + GH_BYTES);
  unsigned short* nx = (unsigned short*)(ws + QK_BYTES + GH_BYTES + CAT_BYTES);
  unsigned short* vT = nx;
  unsigned short* projectT = nx;

  // 0a. expandT'[perm(n)][k] = bf16(expand[k][n])
  tconv_kernel<true><<<dim3(68, 16), 256, 0, stream>>>(expand, expandT, 1024, 4352);
  // 1. LayerNorm
  ln_kernel<<<16384, 256, 0, stream>>>(x, nx);
  // 2a. qk = nx @ expandT'[0:256]^T
  gemm256_kernel<0><<<dim3(64), 512, 0, stream>>>(
      nx, DM, expandT, DM, (void*)qk, nullptr, 256, DM, 1, nullptr);
  // 2b. gated GEMM: local->concat[:, :1024], v->vbuf (gateH eliminated)
  gemm256_kernel<2><<<dim3(64 * 16), 512, 0, stream>>>(
      nx, DM, expandT + (size_t)256 * DM, DM, (void*)concat, (void*)vbuf, 0, DM,
      16, nullptr);
  // 3. v transpose (nx dead after 2b; vT overwrites it)
  vt_kernel<<<dim3(64, 16, 4), 256, 0, stream>>>(vbuf, vT);
  // 4. P = softmax numerator; l zeroed first
  hipMemsetAsync(l, 0, L_BYTES, stream);
  pk_kernel<<<dim3(NBATCH * 528), 512, 0, stream>>>(qk, pbm, P, l);
  // 5. attn = (P @ V) / l -> concat[:, 1024:2048]
  pv_kernel<<<dim3(1024), 256, 0, stream>>>(P, vT, l, concat);
  // 6. projectT (vT dead)
  tconv_kernel<false><<<dim3(16, 32), 256, 0, stream>>>(project, projectT, 2048, DM);
  // 7. out = x + concat @ projectT^T
  gemm256_kernel<1><<<dim3(64 * 4), 512, 0, stream>>>(
      concat, 2048, projectT, 2048, (void*)out, nullptr, DM, 2048, 4, x);
}